// Round 6
// baseline (2003.938 us; speedup 1.0000x reference)
//
#include <hip/hip_runtime.h>
#include <hip/hip_bf16.h>
#include <math.h>

typedef __hip_bfloat16 bf16;
typedef __bf16 bf16x8 __attribute__((ext_vector_type(8)));
typedef float f32x4 __attribute__((ext_vector_type(4)));
typedef short s16x8 __attribute__((ext_vector_type(8)));

#define DIMC 1024
#define TLEN 2048
#define NBATCH 2
#define NHEADS 16
#define NE 8
#define NTOK 4096          // B*T
#define HIDN 4096          // 4*DIM
#define LNEPS 1e-5f

// flag-branched input load: f!=0 -> fp32, else bf16
__device__ __forceinline__ float ldf(const void* p, size_t i, int f) {
    return f ? ((const float*)p)[i] : __bfloat162float(((const bf16*)p)[i]);
}
__device__ __forceinline__ short f2b(float v) {
    bf16 h = __float2bfloat16(v);
    return *reinterpret_cast<short*>(&h);
}
__device__ __forceinline__ float b2f(short s) {
    bf16 h = *reinterpret_cast<bf16*>(&s);
    return __bfloat162float(h);
}
// async global->LDS, 16B per lane. LDS dest: wave-uniform base + lane*16.
__device__ __forceinline__ void gload16(const short* g, short* l) {
    __builtin_amdgcn_global_load_lds(
        (const __attribute__((address_space(1))) void*)g,
        (__attribute__((address_space(3))) void*)l, 16, 0, 0);
}

// ---------------------------------------------------------------- dtype detect
__global__ void detect_kernel(const void* x, int* flag) {
    if (threadIdx.x == 0 && blockIdx.x == 0) {
        const bf16* xb = (const bf16*)x;
        float mx = 0.f;
        for (int i = 0; i < 256; i++) {
            float v = fabsf(__bfloat162float(xb[i]));
            if (isnan(v) || isinf(v)) v = 1e30f;
            mx = fmaxf(mx, v);
        }
        flag[0] = (mx < 1e3f) ? 0 : 1;   // 1 = inputs are fp32
    }
}

// ---------------------------------------------------------------- zero init
__global__ void zero_kernel(float* moe_out, unsigned* counts) {
    int i = blockIdx.x * 256 + threadIdx.x;
    if (i < NTOK * DIMC) moe_out[i] = 0.0f;
    if (i < NE) counts[i] = 0u;
}

// ---------------------------------------------------------------- layernorm
// one block per token. Outputs: fp32 (outf) and/or bf16 split:
// o_hi always when non-null; o_mid/o_lo give 3-way split (fp32-exact repr).
__global__ __launch_bounds__(256) void ln_kernel(const void* xr, const float* xf,
                                                 const void* g, const void* b,
                                                 float* outf, short* o_hi,
                                                 short* o_mid, short* o_lo,
                                                 const int* flag) {
    int f32 = *flag;
    int n = blockIdx.x;
    int tid = threadIdx.x;
    __shared__ float red[256];
    float v[4];
#pragma unroll
    for (int l = 0; l < 4; l++) {
        int c = l * 256 + tid;
        v[l] = xr ? ldf(xr, (size_t)n * DIMC + c, f32) : xf[(size_t)n * DIMC + c];
    }
    float s = v[0] + v[1] + v[2] + v[3];
    red[tid] = s; __syncthreads();
    for (int st = 128; st > 0; st >>= 1) { if (tid < st) red[tid] += red[tid + st]; __syncthreads(); }
    float mu = red[0] * (1.0f / DIMC);
    __syncthreads();
    float s2 = 0.f;
#pragma unroll
    for (int l = 0; l < 4; l++) { float d = v[l] - mu; s2 += d * d; }
    red[tid] = s2; __syncthreads();
    for (int st = 128; st > 0; st >>= 1) { if (tid < st) red[tid] += red[tid + st]; __syncthreads(); }
    float var = red[0] * (1.0f / DIMC);
    float rstd = rsqrtf(var + LNEPS);
#pragma unroll
    for (int l = 0; l < 4; l++) {
        int c = l * 256 + tid;
        size_t idx = (size_t)n * DIMC + c;
        float o = (v[l] - mu) * rstd * ldf(g, c, f32) + ldf(b, c, f32);
        if (outf) outf[idx] = o;
        if (o_hi) {
            short h0 = f2b(o);
            o_hi[idx] = h0;
            if (o_mid) {
                float r = o - b2f(h0);
                short h1 = f2b(r);
                o_mid[idx] = h1;
                o_lo[idx] = f2b(r - b2f(h1));
            }
        }
    }
}

// ---------------------------------------------------------------- unified 128x128 MFMA GEMM
// m97-class structure: BM=BN=128, BK=32, 4 waves (each owns a 64x64 quadrant,
// 4x4 fragments of 16x16x32), LDS-staged via global_load_lds width=16,
// 2 barriers per K-step, LDS chunk XOR-swizzle (slot = chunk ^ ((row>>1)&3))
// applied identically on the pre-swizzled global source and the ds_read.
// Fragment layout (verified m89): A[m=lane&15][k=quad*8+j]; B[k][n=lane&15];
// C/D col=lane&15, row=quad*4+reg.
//
// MODE 1: C = (A0+A1+A2) @ Bt^T (+resid)  -- 3-way split A, fp32 out (qkv/proj)
//         flag!=0 (fp32 weights): adds (A0+A1)*Blo terms (Blo direct-global).
// MODE 2: he[slot] = gelu(A[tok(slot)] @ Bt[e]^T + bias[e])  -> bf16 out
// MODE 3: moe[tok] += topw[slot] * (A[off+slot] @ Bt[e]^T)   -> atomic f32
template<int MODE>
__global__ __launch_bounds__(256) void gemm128(
    const short* __restrict__ A0, const short* __restrict__ A1,
    const short* __restrict__ A2,
    const short* __restrict__ Bt, const short* __restrict__ Blo,
    const void* __restrict__ resid, float* __restrict__ Cf,
    short* __restrict__ Cb, const void* __restrict__ bias,
    const int* __restrict__ perm, const unsigned* __restrict__ counts,
    const unsigned* __restrict__ offsets, const float* __restrict__ topw,
    float* __restrict__ moe_out,
    int N, int K, const int* flag)
{
    constexpr int NT = (MODE == 1) ? 4 : 2;       // A tiles (1 or 3) + B tile
    __shared__ __align__(16) short tiles[NT * 4096];   // each tile: 128 rows x 32 k
    __shared__ int tokLs[128];
    __shared__ float wLs[128];

    int e = (MODE >= 2) ? blockIdx.z : 0;
    int m0 = blockIdx.y * 128, n0 = blockIdx.x * 128;
    int cnt = 0; unsigned off = 0;
    if (MODE >= 2) {
        cnt = (int)counts[e];
        if (m0 >= cnt) return;
        off = offsets[e];
    }
    int tid = threadIdx.x;
    int f32 = *flag;

    if (MODE >= 2) {
        if (tid < 128) {
            int rr = m0 + tid; if (rr >= cnt) rr = cnt - 1;
            int pair = perm[off + rr];
            tokLs[tid] = pair >> 1;
            wLs[tid] = topw[pair];
        }
        __syncthreads();
    }

    // ---- staging setup: thread stages LDS chunks (tid) and (tid+256) of each
    // tile; chunk L -> row L>>2, slot L&3; content = global chunk slot^((row>>1)&3).
    int r0 = tid >> 2;                        // rows r0 and r0+64 (same swizzle)
    int c0 = (tid & 3) ^ ((r0 >> 1) & 3);     // swizzled global chunk
    int wb = (tid & 192) * 8;                 // wave-uniform LDS elem base (instr 0)
    size_t cofs = (size_t)c0 * 8;

    const short* BTe = (MODE >= 2) ? Bt + (size_t)e * N * K : Bt;
    const short* gb0 = BTe + (size_t)(n0 + r0) * K + cofs;
    const short* gb1 = BTe + (size_t)(n0 + r0 + 64) * K + cofs;

    size_t arow0, arow1;
    if (MODE == 1)      { arow0 = m0 + r0;      arow1 = m0 + r0 + 64; }
    else if (MODE == 2) { arow0 = tokLs[r0];    arow1 = tokLs[r0 + 64]; }
    else {
        int rr0 = m0 + r0;      if (rr0 >= cnt) rr0 = cnt - 1;
        int rr1 = m0 + r0 + 64; if (rr1 >= cnt) rr1 = cnt - 1;
        arow0 = off + rr0; arow1 = off + rr1;
    }
    const short* ga0 = A0 + arow0 * K + cofs;
    const short* ga1 = A0 + arow1 * K + cofs;
    const short *gm0 = nullptr, *gm1 = nullptr, *gl0 = nullptr, *gl1 = nullptr;
    if (MODE == 1) {
        gm0 = A1 + arow0 * K + cofs; gm1 = A1 + arow1 * K + cofs;
        gl0 = A2 + arow0 * K + cofs; gl1 = A2 + arow1 * K + cofs;
    }

    short* tA0 = tiles;
    short* tA1 = tiles + 4096;
    short* tA2 = tiles + 8192;
    short* tB  = tiles + (NT - 1) * 4096;

    // ---- fragment read offsets (constant across K-steps)
    int w = tid >> 6, lane = tid & 63, quad = lane >> 4, l15 = lane & 15;
    int wm = (w >> 1) * 64, wn = (w & 1) * 64;
    int offA[4], offB[4];
#pragma unroll
    for (int i = 0; i < 4; i++) {
        int ra = wm + i * 16 + l15;
        offA[i] = ra * 32 + ((quad ^ ((ra >> 1) & 3)) * 8);
        int rb = wn + i * 16 + l15;
        offB[i] = rb * 32 + ((quad ^ ((rb >> 1) & 3)) * 8);
    }

    f32x4 acc[4][4];
#pragma unroll
    for (int i = 0; i < 4; i++)
#pragma unroll
        for (int j = 0; j < 4; j++) acc[i][j] = (f32x4){0.f, 0.f, 0.f, 0.f};

    for (int kt = 0; kt < K; kt += 32) {
        if (kt) __syncthreads();               // prev compute done reading LDS
        if (MODE == 1) {
            gload16(ga0 + kt, tA0 + wb); gload16(ga1 + kt, tA0 + wb + 2048);
            gload16(gm0 + kt, tA1 + wb); gload16(gm1 + kt, tA1 + wb + 2048);
            gload16(gl0 + kt, tA2 + wb); gload16(gl1 + kt, tA2 + wb + 2048);
        } else {
            gload16(ga0 + kt, tA0 + wb); gload16(ga1 + kt, tA0 + wb + 2048);
        }
        gload16(gb0 + kt, tB + wb); gload16(gb1 + kt, tB + wb + 2048);
        __syncthreads();                       // vmcnt(0) drain: LDS tile ready

        bf16x8 b[4];
#pragma unroll
        for (int ni = 0; ni < 4; ni++) b[ni] = *(const bf16x8*)(tB + offB[ni]);
        if (MODE == 1) {
#pragma unroll
            for (int mi = 0; mi < 4; mi++) {
                bf16x8 ah = *(const bf16x8*)(tA0 + offA[mi]);
                bf16x8 am = *(const bf16x8*)(tA1 + offA[mi]);
                bf16x8 al = *(const bf16x8*)(tA2 + offA[mi]);
#pragma unroll
                for (int ni = 0; ni < 4; ni++) {
                    acc[mi][ni] = __builtin_amdgcn_mfma_f32_16x16x32_bf16(ah, b[ni], acc[mi][ni], 0, 0, 0);
                    acc[mi][ni] = __builtin_amdgcn_mfma_f32_16x16x32_bf16(am, b[ni], acc[mi][ni], 0, 0, 0);
                    acc[mi][ni] = __builtin_amdgcn_mfma_f32_16x16x32_bf16(al, b[ni], acc[mi][ni], 0, 0, 0);
                }
            }
            if (f32) {   // fp32 weights: B-lo terms, direct-global (correctness path)
#pragma unroll
                for (int ni = 0; ni < 4; ni++) {
                    bf16x8 bl = *(const bf16x8*)(Blo + (size_t)(n0 + wn + ni * 16 + l15) * K + kt + quad * 8);
#pragma unroll
                    for (int mi = 0; mi < 4; mi++) {
                        bf16x8 ah = *(const bf16x8*)(tA0 + offA[mi]);
                        bf16x8 am = *(const bf16x8*)(tA1 + offA[mi]);
                        acc[mi][ni] = __builtin_amdgcn_mfma_f32_16x16x32_bf16(ah, bl, acc[mi][ni], 0, 0, 0);
                        acc[mi][ni] = __builtin_amdgcn_mfma_f32_16x16x32_bf16(am, bl, acc[mi][ni], 0, 0, 0);
                    }
                }
            }
        } else {
#pragma unroll
            for (int mi = 0; mi < 4; mi++) {
                bf16x8 a = *(const bf16x8*)(tA0 + offA[mi]);
#pragma unroll
                for (int ni = 0; ni < 4; ni++)
                    acc[mi][ni] = __builtin_amdgcn_mfma_f32_16x16x32_bf16(a, b[ni], acc[mi][ni], 0, 0, 0);
            }
        }
    }

    // ---- epilogue (layouts identical to R3-verified kernels)
#pragma unroll
    for (int mi = 0; mi < 4; mi++) {
#pragma unroll
        for (int ni = 0; ni < 4; ni++) {
            int col = n0 + wn + ni * 16 + l15;
#pragma unroll
            for (int reg = 0; reg < 4; reg++) {
                int rl = wm + mi * 16 + quad * 4 + reg;   // local row
                float val = acc[mi][ni][reg];
                if (MODE == 1) {
                    int row = m0 + rl;
                    float rv = resid ? ldf(resid, (size_t)row * N + col, f32) : 0.0f;
                    Cf[(size_t)row * N + col] = val + rv;
                } else if (MODE == 2) {
                    if (m0 + rl < cnt) {
                        val += ldf(bias, (size_t)e * N + col, f32);
                        val = 0.5f * val * (1.0f + erff(val * 0.70710678118f));
                        Cb[((size_t)off + m0 + rl) * N + col] = f2b(val);
                    }
                } else {
                    if (m0 + rl < cnt)
                        atomicAdd(&moe_out[(size_t)tokLs[rl] * N + col], val * wLs[rl]);
                }
            }
        }
    }
}

// ---------------------------------------------------------------- attention: fp32 tiled flash
// grid (TLEN/64 reversed, B*H), 256 threads. 64 queries/block, 4 lanes/query
// (dpart owns 16 dims). K/V staged in LDS, 64-key tiles.
// Inner loop batches 16 keys per online-softmax step: 16 independent dots,
// one chunk max, ONE branch-free rescale (alpha=exp(m-mn), ==1 if no new max),
// 16 independent exps, 256 independent PV FMAs. Same flash recurrence in fp32.
#define KB 64
#define KSTRIDE 72   // pad 64->72 floats: staging writes 2-way, reads conflict-free

__global__ __launch_bounds__(256) void attn_kernel(const float* __restrict__ qkv,
                                                   short* __restrict__ yhi,
                                                   short* __restrict__ ymid,
                                                   short* __restrict__ ylo) {
    int qblk = gridDim.x - 1 - blockIdx.x;   // longest causal blocks first
    int bh = blockIdx.y; int b = bh >> 4, h = bh & 15;
    int tid = threadIdx.x;
    int lane = tid & 63;
    int wave = tid >> 6;
    int qid = lane & 15;       // query within wave
    int dpart = lane >> 4;     // 0..3: owns dims dpart*16..dpart*16+15
    int q = qblk * 64 + wave * 16 + qid;

    __shared__ float Ks[KB * KSTRIDE];
    __shared__ float Vs[KB * KSTRIDE];

    const float* base = qkv + (size_t)b * TLEN * 3 * DIMC;

    float qv[16];
    {
        const float* qrow = base + (size_t)q * 3 * DIMC + h * 64 + dpart * 16;
#pragma unroll
        for (int j = 0; j < 16; j++) qv[j] = qrow[j] * 0.125f;   // 1/sqrt(64)
    }
    float acc[16];
#pragma unroll
    for (int j = 0; j < 16; j++) acc[j] = 0.f;
    float m = -INFINITY, l = 0.f;

    int ntiles = qblk + 1;                 // causal: keys 0 .. qblk*64+63
    for (int t = 0; t < ntiles; t++) {
        int k0 = t * KB;
        __syncthreads();                   // protect previous tile's readers
#pragma unroll
        for (int p4 = 0; p4 < 4; p4++) {
            int idx = tid + p4 * 256;
            int r = idx >> 4, c4 = idx & 15;
            const float* krow = base + (size_t)(k0 + r) * 3 * DIMC + DIMC + h * 64 + c4 * 4;
            *(f32x4*)&Ks[r * KSTRIDE + c4 * 4] = *(const f32x4*)krow;
            *(f32x4*)&Vs[r * KSTRIDE + c4 * 4] = *(const f32x4*)(krow + DIMC);
        }
        __syncthreads();
        bool diag = (t == ntiles - 1);
        for (int cb = 0; cb < KB; cb += 16) {
            float p[16];
#pragma unroll
            for (int c = 0; c < 16; c++) {               // 16 independent dots
                const float* kr = &Ks[(cb + c) * KSTRIDE + dpart * 16];
                f32x4 k0v = *(const f32x4*)(kr);
                f32x4 k1v = *(const f32x4*)(kr + 4);
                f32x4 k2v = *(const f32x4*)(kr + 8);
                f32x4 k3v = *(const f32x4*)(kr + 12);
                float s0 = 0.f, s1 = 0.f, s2 = 0.f, s3 = 0.f;
#pragma unroll
                for (int j = 0; j < 4; j++) {
                    s0 += qv[j]      * k0v[j];
                    s1 += qv[4 + j]  * k1v[j];
                    s2 += qv[8 + j]  * k2v[j];
                    s3 += qv[12 + j] * k3v[j];
                }
                float pp = (s0 + s1) + (s2 + s3);
                pp += __shfl_xor(pp, 16);  // reduce across the 4 dim-partitions
                pp += __shfl_xor(pp, 32);
                p[c] = pp;
            }
            if (diag) {
#pragma unroll
                for (int c = 0; c < 16; c++)
                    if (k0 + cb + c > q) p[c] = -INFINITY;
            }
            float pmax = fmaxf(p[0], p[1]);
#pragma unroll
            for (int c = 2; c < 16; c++) pmax = fmaxf(pmax, p[c]);
            float mn = fmaxf(m, pmax);
            float alpha = __expf(m - mn);                // ==1 when no new max
#pragma unroll
            for (int c = 0; c < 16; c++) p[c] = __expf(p[c] - mn);
            float ws = 0.f;
#pragma unroll
            for (int c = 0; c < 16; c++) ws += p[c];
            l = l * alpha + ws;
#pragma unroll
            for (int j = 0; j < 16; j++) acc[j] *= alpha;
#pragma unroll
            for (int c = 0; c < 16; c++) {               // 256 independent FMAs
                const float* vr = &Vs[(cb + c) * KSTRIDE + dpart * 16];
#pragma unroll
                for (int cc = 0; cc < 4; cc++) {
                    f32x4 vc = *(const f32x4*)(vr + cc * 4);
#pragma unroll
                    for (int j = 0; j < 4; j++) acc[cc * 4 + j] += p[c] * vc[j];
                }
            }
            m = mn;
        }
    }

    float invl = 1.0f / l;
    size_t rowbase = (size_t)(b * TLEN + q) * DIMC + h * 64 + dpart * 16;
#pragma unroll
    for (int half = 0; half < 2; half++) {
        s16x8 oh, om, ol;
#pragma unroll
        for (int j = 0; j < 8; j++) {
            float v = acc[half * 8 + j] * invl;
            short h0 = f2b(v);
            float r = v - b2f(h0);
            short h1 = f2b(r);
            oh[j] = h0; om[j] = h1; ol[j] = f2b(r - b2f(h1));
        }
        *(s16x8*)(yhi  + rowbase + half * 8) = oh;
        *(s16x8*)(ymid + rowbase + half * 8) = om;
        *(s16x8*)(ylo  + rowbase + half * 8) = ol;
    }
}

// ---------------------------------------------------------------- router (fp32-exact)
__global__ __launch_bounds__(256) void router_kernel(const float* __restrict__ h2,
                                                     const void* __restrict__ wr,
                                                     int* topi, float* topw,
                                                     unsigned* counts, const int* flag) {
    int f32 = *flag;
    int n = blockIdx.x, tid = threadIdx.x;
    __shared__ float sm[NE][256];
    float p[NE] = {};
#pragma unroll
    for (int l = 0; l < 4; l++) {
        int dd = l * 256 + tid;
        float hv = h2[(size_t)n * DIMC + dd];
#pragma unroll
        for (int e = 0; e < NE; e++) p[e] += hv * ldf(wr, (size_t)dd * NE + e, f32);
    }
#pragma unroll
    for (int e = 0; e < NE; e++) sm[e][tid] = p[e];
    __syncthreads();
    for (int st = 128; st > 0; st >>= 1) {
        if (tid < st)
#pragma unroll
            for (int e = 0; e < NE; e++) sm[e][tid] += sm[e][tid + st];
        __syncthreads();
    }
    if (tid == 0) {
        float lg[NE];
#pragma unroll
        for (int e = 0; e < NE; e++) lg[e] = sm[e][0];
        int i0 = 0;
        for (int e = 1; e < NE; e++) if (lg[e] > lg[i0]) i0 = e;
        int i1 = -1;
        for (int e = 0; e < NE; e++)
            if (e != i0 && (i1 < 0 || lg[e] > lg[i1])) i1 = e;
        float e1 = __expf(lg[i1] - lg[i0]);
        float inv = 1.0f / (1.0f + e1);
        topi[n * 2] = i0; topi[n * 2 + 1] = i1;
        topw[n * 2] = inv; topw[n * 2 + 1] = e1 * inv;
        atomicAdd(&counts[i0], 1u);
        atomicAdd(&counts[i1], 1u);
    }
}

__global__ void offsets_kernel(const unsigned* counts, unsigned* offsets, unsigned* cursor) {
    if (threadIdx.x == 0 && blockIdx.x == 0) {
        unsigned s = 0;
        for (int e = 0; e < NE; e++) { offsets[e] = s; s += counts[e]; cursor[e] = 0u; }
    }
}

__global__ void scatter_kernel(const int* topi, const unsigned* offsets,
                               unsigned* cursor, int* perm) {
    int n = blockIdx.x * 256 + threadIdx.x;
    if (n >= NTOK) return;
    for (int s = 0; s < 2; s++) {
        int e = topi[n * 2 + s];
        unsigned pos = atomicAdd(&cursor[e], 1u);
        perm[offsets[e] + pos] = n * 2 + s;
    }
}

// ---------------------------------------------------------------- transpose+cast to bf16
// in: raw (flag dtype) [z][R][C] -> out bf16 [z][C][R]; optional 2-way split lo.
__global__ __launch_bounds__(256) void transpose_kernel(const void* __restrict__ in,
                                                        short* __restrict__ out,
                                                        short* __restrict__ out_lo,
                                                        int R, int C, const int* flag) {
    int f32 = *flag;
    __shared__ float t[32][33];
    int r0 = blockIdx.y * 32, c0 = blockIdx.x * 32;
    size_t base = (size_t)blockIdx.z * R * C;
    int tx = threadIdx.x & 31, ty = threadIdx.x >> 5;   // 32 x 8
#pragma unroll
    for (int i = ty; i < 32; i += 8)
        t[i][tx] = ldf(in, base + (size_t)(r0 + i) * C + c0 + tx, f32);
    __syncthreads();
#pragma unroll
    for (int i = ty; i < 32; i += 8) {
        float v = t[tx][i];
        short h0 = f2b(v);
        size_t idx = base + (size_t)(c0 + i) * R + r0 + tx;
        out[idx] = h0;
        if (out_lo) out_lo[idx] = f2b(v - b2f(h0));
    }
}

// ---------------------------------------------------------------- final: out = x2 + moe + sum_s w_s*b2[e_s]
__global__ void final_kernel(const float* x2, const float* moe,
                             const int* topi, const float* topw,
                             const void* b2, void* out, const int* flag) {
    int f32 = *flag;
    int i = blockIdx.x * 256 + threadIdx.x;
    int n = i >> 10, c = i & 1023;
    float v = x2[i] + moe[i];
#pragma unroll
    for (int s = 0; s < 2; s++)
        v += topw[n * 2 + s] * ldf(b2, (size_t)topi[n * 2 + s] * DIMC + c, f32);
    if (f32) ((float*)out)[i] = v;
    else     ((bf16*)out)[i] = __float2bfloat16(v);
}

// ================================================================ launch
extern "C" void kernel_launch(void* const* d_in, const int* in_sizes, int n_in,
                              void* d_out, int out_size, void* d_ws, size_t ws_size,
                              hipStream_t stream) {
    const void* x      = d_in[0];
    const void* ln1_g  = d_in[1];
    const void* ln1_b  = d_in[2];
    const void* w_attn = d_in[3];
    const void* w_proj = d_in[4];
    const void* ln2_g  = d_in[5];
    const void* ln2_b  = d_in[6];
    const void* w_rout = d_in[7];
    const void* w1     = d_in[8];
    const void* b1     = d_in[9];
    const void* w2     = d_in[10];
    const void* b2     = d_in[11];

    const size_t MT = (size_t)NTOK * DIMC;   // 4 M elements
    const size_t MB = 1u << 20;
    char* cws = (char*)d_ws;
    // ---- byte-offset workspace map (high-water 188.25 MB) ----
    short* hhi    = (short*)(cws + 0 * MB);      // MT bf16
    short* hmid   = (short*)(cws + 8 * MB);
    short* hlo    = (short*)(cws + 16 * MB);
    short* wat_hi = (short*)(cws + 24 * MB);     // 3*DIMC*DIMC bf16 (6 MB)
    short* wat_lo = (short*)(cws + 30 * MB);
    float* qkv    = (float*)(cws + 36 * MB);     // 3*MT fp32 (48 MB)
    short* yhi    = (short*)(cws + 0 * MB);      // reuse h split
    short* ymid   = (short*)(cws + 8 * MB);
    short* ylo    = (short*)(cws + 16 * MB);
    short* wpt_hi = (short*)(cws + 24 * MB);     // DIMC*DIMC bf16 (2 MB)
    short* wpt_lo = (short*)(cws + 26 * MB);
    float* h2     = (float*)(cws + 36 * MB);     // MT fp32 (reuse qkv; dead after router)
    short* he     = (short*)(cws + 0 * MB);      // 2*NTOK x HIDN bf16 (64 MB)
    float* x2     = (float*)(cws + 84 * MB);     // MT fp32
    float* moe    = (float*)(cws + 100 * MB);    // MT fp32
    int*      topi    = (int*)(cws + 116 * MB);          // 32 KB
    float*    topw    = (float*)(topi + 2 * NTOK);       // 32 KB
    unsigned* counts  = (unsigned*)(topw + 2 * NTOK);    // 32 B
    unsigned* offsets = counts + NE;
    unsigned* cursor  = offsets + NE;
    int*      perm    = (int*)(cursor + NE);             // 32 KB
    int*      flag    = (int*)(perm + 2 * NTOK);
    short* h2b  = (short*)(cws + 116 * MB + 256 * 1024); // MT bf16 (8 MB)
    short* w12t = (short*)(cws + 116 * MB + 256 * 1024 + 8 * MB); // 64 MB

    // 0. detect input dtype
    detect_kernel<<<1, 64, 0, stream>>>(x, flag);
    // 1. zero moe accumulator + expert counts
    zero_kernel<<<dim3((MT + 255) / 256), 256, 0, stream>>>(moe, counts);
    // 2. LN1 -> h as 3-way bf16 split (fp32-exact representation)
    ln_kernel<<<NTOK, 256, 0, stream>>>(x, nullptr, ln1_g, ln1_b,
                                        nullptr, hhi, hmid, hlo, flag);
    // 3. w_attnt[3C][C] = w_attn[C][3C]^T  (bf16 hi + lo)
    transpose_kernel<<<dim3(3 * DIMC / 32, DIMC / 32, 1), 256, 0, stream>>>(
        w_attn, wat_hi, wat_lo, DIMC, 3 * DIMC, flag);
    // 4. qkv = h @ w_attn (split MFMA, fp32-grade)
    gemm128<1><<<dim3(3 * DIMC / 128, NTOK / 128), 256, 0, stream>>>(
        hhi, hmid, hlo, wat_hi, wat_lo, nullptr, qkv,
        nullptr, nullptr, nullptr, nullptr, nullptr, nullptr, nullptr,
        3 * DIMC, DIMC, flag);
    // 5. attention (fp32 tiled flash, 16-key-batched softmax) -> y split
    attn_kernel<<<dim3(TLEN / 64, NBATCH * NHEADS), 256, 0, stream>>>(qkv, yhi, ymid, ylo);
    // 6. w_projt[C][C] = w_proj[C][C]^T  (bf16 hi + lo)
    transpose_kernel<<<dim3(DIMC / 32, DIMC / 32, 1), 256, 0, stream>>>(
        w_proj, wpt_hi, wpt_lo, DIMC, DIMC, flag);
    // 7. x2 = x + y @ w_proj (split MFMA)
    gemm128<1><<<dim3(DIMC / 128, NTOK / 128), 256, 0, stream>>>(
        yhi, ymid, ylo, wpt_hi, wpt_lo, x, x2,
        nullptr, nullptr, nullptr, nullptr, nullptr, nullptr, nullptr,
        DIMC, DIMC, flag);
    // 8. LN2 -> h2 (fp32, router) + h2b (bf16, experts)
    ln_kernel<<<NTOK, 256, 0, stream>>>(nullptr, x2, ln2_g, ln2_b,
                                        h2, h2b, nullptr, nullptr, flag);
    // 9. router + top-2 (fp32-exact)
    router_kernel<<<NTOK, 256, 0, stream>>>(h2, w_rout, topi, topw, counts, flag);
    // 10. prefix offsets
    offsets_kernel<<<1, 64, 0, stream>>>(counts, offsets, cursor);
    // 11. scatter token-slot ids by expert
    scatter_kernel<<<NTOK / 256, 256, 0, stream>>>(topi, offsets, cursor, perm);
    // 12. w1t[e][HIDN][DIMC] = w1[e][DIMC][HIDN]^T  (bf16)
    transpose_kernel<<<dim3(HIDN / 32, DIMC / 32, NE), 256, 0, stream>>>(
        w1, w12t, nullptr, DIMC, HIDN, flag);
    // 13. GEMM1: he = gelu(gather(h2b) @ w1t^T + b1)
    gemm128<2><<<dim3(HIDN / 128, NTOK / 128, NE), 256, 0, stream>>>(
        h2b, nullptr, nullptr, w12t, nullptr, nullptr, nullptr,
        he, b1, perm, counts, offsets, topw, nullptr, HIDN, DIMC, flag);
    // 14. w2t[e][DIMC][HIDN] = w2[e][HIDN][DIMC]^T  (bf16, reuses w1t buffer)
    transpose_kernel<<<dim3(DIMC / 32, HIDN / 32, NE), 256, 0, stream>>>(
        w2, w12t, nullptr, HIDN, DIMC, flag);
    // 15. GEMM2: moe[tok] += topw * (he @ w2t^T)
    gemm128<3><<<dim3(DIMC / 128, NTOK / 128, NE), 256, 0, stream>>>(
        he, nullptr, nullptr, w12t, nullptr, nullptr, nullptr,
        nullptr, nullptr, perm, counts, offsets, topw, moe, DIMC, HIDN, flag);
    // 16. out = x2 + moe + sum_s w_s * b2[e_s]
    final_kernel<<<dim3((MT + 255) / 256), 256, 0, stream>>>(x2, moe, topi, topw, b2,
                                                             (void*)d_out, flag);
}